// Round 8
// baseline (40.224 us; speedup 1.0000x reference)
//
#include <hip/hip_runtime.h>

#define BINS 10
#define TPB  256
#define NB_MAX 2048
#define FTPB 1024   // finalize block size
#define KPACK 4096.0f

// Pass 1: per-bin (count,sum) fused into ONE accumulator per bin:
//   acc[b] += (bin==b) ? (bce + 4096) : 0
// Per-thread S_b < 160 << 4096, so epilogue separation C=floor(acc/4096),
// S=acc-4096*C is exact to ~1e-5 relative on the final loss.
// One-hot select: sel = sbfe(1<<bin, b, 1) in {0,-1}; acc[b] += sel & v.
// Depth-2 software pipeline: 6 dwordx4 loads (2 quads ahead) in flight under
// every 4-element proc window -- the round-7 depth-1 version exposed
// ~300 cyc of load latency per quad (flat 43-46us, no pipe saturated).
__global__ __launch_bounds__(TPB, 4) void ghmc_hist_kernel(
    const float4* __restrict__ pred4,
    const int4*   __restrict__ tgt4,
    const int4*   __restrict__ lw4,
    float* __restrict__ part,      // [nb][2*BINS]
    int n4, int n)
{
    float acc[BINS];
#pragma unroll
    for (int b = 0; b < BINS; ++b) acc[b] = 0.f;

    auto proc = [&](float p, int t, int w) {
        // q = t ? -p : p  ==>  sigmoid(q) = g,  softplus(q) = bce
        float q     = __int_as_float(__float_as_int(p) ^ (t << 31));
        float e     = __expf(-fabsf(q));          // exp(-|q|) in (0,1]
        float d     = 1.f + e;
        float r     = __builtin_amdgcn_rcpf(d);
        float num   = (q >= 0.f) ? 1.0f : e;      // sigmoid numerator
        float sig10 = num * (10.f * r);           // 10*sigmoid(q) in [0,10]
        int bin     = (int)sig10;
        bin = bin < (BINS - 1) ? bin : (BINS - 1);
        float bce   = fmaxf(q, 0.f) + __logf(d);  // softplus(q)
        float v     = (w > 0) ? (bce + KPACK) : 0.f;
        int bit     = 1 << bin;
        int vbits   = __float_as_int(v);
#pragma unroll
        for (int b = 0; b < BINS; ++b) {
            int sel = __builtin_amdgcn_sbfe(bit, b, 1);   // {0,-1}
            acc[b] += __int_as_float(sel & vbits);
        }
    };

    const int tid    = threadIdx.x;
    const int stride = gridDim.x * TPB;
    const int base   = blockIdx.x * TPB + tid;
    const int full   = n4 / stride;   // uniform trip count (5 at N=10.49M)

    struct Quad { float4 p; int4 t, w; };
    auto LD = [&](int idx) {
        Quad q;
        q.p = pred4[idx]; q.t = tgt4[idx]; q.w = lw4[idx];
        return q;
    };
    auto proc4 = [&](const Quad& q) {
        proc(q.p.x, q.t.x, q.w.x); proc(q.p.y, q.t.y, q.w.y);
        proc(q.p.z, q.t.z, q.w.z); proc(q.p.w, q.t.w, q.w.w);
    };

    if (full >= 2) {
        Quad A = LD(base);
        Quad B = LD(base + stride);
        int i = base + 2 * stride;
#pragma unroll 2
        for (int k = 0; k < full - 2; ++k, i += stride) {
            Quad C = LD(i);        // issued before proc: 6 loads in flight
            proc4(A);
            A = B; B = C;          // coalesced by regalloc (A dead)
        }
        proc4(A);
        proc4(B);
    } else if (full == 1) {
        Quad A = LD(base);
        proc4(A);
    }
    // remainder quad (threads with one extra quad; cold at this shape)
    {
        const int j = base + full * stride;
        if (j < n4) { Quad A = LD(j); proc4(A); }
    }
    // scalar tail (n not divisible by 4; cold at this shape)
    if (blockIdx.x == 0 && tid < (n & 3)) {
        const float* predf = (const float*)pred4;
        const int*   tgtf  = (const int*)tgt4;
        const int*   lwf   = (const int*)lw4;
        const int j = n4 * 4 + tid;
        proc(predf[j], tgtf[j], lwf[j]);
    }

    // separate counts and sums (exact; see header comment)
    float s_[BINS], c_[BINS];
#pragma unroll
    for (int b = 0; b < BINS; ++b) {
        float Cf = floorf(acc[b] * (1.f / KPACK));
        c_[b] = Cf;
        s_[b] = acc[b] - KPACK * Cf;
    }

    // 4-level xor reduce within 16-lane groups
#pragma unroll
    for (int b = 0; b < BINS; ++b) {
#pragma unroll
        for (int off = 1; off <= 8; off <<= 1) {
            s_[b] += __shfl_xor(s_[b], off, 64);
            c_[b] += __shfl_xor(c_[b], off, 64);
        }
    }

    // 16 group leaders -> tiny LDS -> 20 threads write the block record
    __shared__ float red[2 * BINS][16];   // 1.28 KB
    const int grp = tid >> 4;
    if ((tid & 15) == 0) {
#pragma unroll
        for (int b = 0; b < BINS; ++b) {
            red[b][grp]        = s_[b];
            red[BINS + b][grp] = c_[b];
        }
    }
    __syncthreads();
    if (tid < 2 * BINS) {
        float v = 0.f;
#pragma unroll
        for (int g = 0; g < 16; ++g) v += red[tid][g];
        part[blockIdx.x * (2 * BINS) + tid] = v;   // contiguous record
    }
}

// Pass 2: reduce nb 20-float records with full ILP, compute the scalar loss.
__global__ __launch_bounds__(FTPB) void ghmc_final_kernel(
    const float* __restrict__ part, float* __restrict__ out, int nb)
{
    float acc[2 * BINS];
#pragma unroll
    for (int v = 0; v < 2 * BINS; ++v) acc[v] = 0.f;

    const int tid = threadIdx.x;
    for (int i = tid; i < nb; i += FTPB) {
        const float4* rec = (const float4*)(part + (size_t)i * (2 * BINS));
        float4 a = rec[0], b = rec[1], c = rec[2], d = rec[3], e = rec[4];
        acc[0]  += a.x; acc[1]  += a.y; acc[2]  += a.z; acc[3]  += a.w;
        acc[4]  += b.x; acc[5]  += b.y; acc[6]  += b.z; acc[7]  += b.w;
        acc[8]  += c.x; acc[9]  += c.y; acc[10] += c.z; acc[11] += c.w;
        acc[12] += d.x; acc[13] += d.y; acc[14] += d.z; acc[15] += d.w;
        acc[16] += e.x; acc[17] += e.y; acc[18] += e.z; acc[19] += e.w;
    }

#pragma unroll
    for (int v = 0; v < 2 * BINS; ++v) {
#pragma unroll
        for (int off = 1; off <= 32; off <<= 1)
            acc[v] += __shfl_xor(acc[v], off, 64);
    }

    __shared__ float sh[2 * BINS][16];
    const int wv = tid >> 6, lane = tid & 63;
    if (lane == 0) {
#pragma unroll
        for (int v = 0; v < 2 * BINS; ++v) sh[v][wv] = acc[v];
    }
    __syncthreads();
    if (tid < 2 * BINS) {
        float s = 0.f;
#pragma unroll
        for (int g = 0; g < 16; ++g) s += sh[tid][g];
        sh[tid][0] = s;
    }
    __syncthreads();

    if (tid == 0) {
        float ti = 0.f; int nbn = 0;
        float cnts[BINS];
#pragma unroll
        for (int b = 0; b < BINS; ++b) {
            cnts[b] = sh[BINS + b][0];
            ti += cnts[b];
            nbn += (cnts[b] > 0.f) ? 1 : 0;
        }
        float total = fmaxf(ti, 1.f);
        float nf    = (float)(nbn > 0 ? nbn : 1);
        float loss  = 0.f;
#pragma unroll
        for (int b = 0; b < BINS; ++b) {
            if (cnts[b] > 0.f) {
                float w = (total / cnts[b]) / nf;   // w_bin[b]
                loss += w * sh[b][0];
            }
        }
        out[0] = loss / total * 1.0f;  // LOSS_WEIGHT = 1.0
    }
}

extern "C" void kernel_launch(void* const* d_in, const int* in_sizes, int n_in,
                              void* d_out, int out_size, void* d_ws, size_t ws_size,
                              hipStream_t stream)
{
    const float4* pred4 = (const float4*)d_in[0];
    const int4*   tgt4  = (const int4*)d_in[1];
    const int4*   lw4   = (const int4*)d_in[2];

    const int n  = in_sizes[0];
    const int n4 = n / 4;

    int nb = (n4 + TPB - 1) / TPB;
    if (nb > NB_MAX) nb = NB_MAX;
    int ws_cap = (int)(ws_size / (2 * BINS * sizeof(float)));
    if (nb > ws_cap) nb = ws_cap;
    if (nb < 1) nb = 1;

    float* part = (float*)d_ws;   // [nb][2*BINS]

    ghmc_hist_kernel<<<nb, TPB, 0, stream>>>(pred4, tgt4, lw4, part, n4, n);
    ghmc_final_kernel<<<1, FTPB, 0, stream>>>(part, (float*)d_out, nb);
}